// Round 11
// baseline (276.971 us; speedup 1.0000x reference)
//
#include <hip/hip_runtime.h>
#include <hip/hip_fp16.h>

#define T_DIM 7
#define H_DIM 96
#define W_DIM 96
#define HW    (H_DIM*W_DIM)          // 9216
#define L_DIM (T_DIM*HW)             // 64512
#define NTAPS 27

typedef __attribute__((ext_vector_type(8))) _Float16 f16x8;
typedef __attribute__((ext_vector_type(4))) float f32x4;

// barrier that does NOT drain vmcnt (keeps global prefetches in flight)
__device__ __forceinline__ void lds_barrier() {
    asm volatile("s_waitcnt lgkmcnt(0)" ::: "memory");
    __builtin_amdgcn_s_barrier();
    __builtin_amdgcn_sched_barrier(0);
}

// async global->LDS, 16B/lane: LDS dest = wave-uniform base (+ lane*16 by HW)
#define GLOAD16(gp, lp) \
    __builtin_amdgcn_global_load_lds((const __attribute__((address_space(1))) unsigned int*)(gp), \
                                     (__attribute__((address_space(3))) unsigned int*)(lp), 16, 0, 0)

// ---------------------------------------------------------------------------
// prep_weights: [O][C][27] fp32 -> [27][O(64-pad)][C] f16, 16B slot rotated by o
// ---------------------------------------------------------------------------
__global__ void prep_weights(const float* __restrict__ woff0,
                             const float* __restrict__ w0,
                             const float* __restrict__ woff1,
                             const float* __restrict__ w1,
                             unsigned short* __restrict__ dst)
{
    int idx = blockIdx.x * 256 + threadIdx.x;
    const int per = NTAPS * 64 * 64;           // 110592
    if (idx >= 4 * per) return;
    int which = idx / per;
    int r     = idx % per;
    int tap   = r / 4096;
    int o     = (r >> 6) & 63;
    int c     = r & 63;
    const float* src = (which == 0) ? woff0 : (which == 1) ? w0
                     : (which == 2) ? woff1 : w1;
    int omax = (which == 0 || which == 2) ? 54 : 64;
    float v = 0.f;
    if (o < omax) v = src[(o * 64 + c) * NTAPS + tap];
    __half h = __float2half(v);
    int slot = (((c >> 3) + o) & 7);
    int pos  = tap * 4096 + o * 64 + slot * 8 + (c & 7);
    dst[which * per + pos] = __half_as_ushort(h);
}

// ---------------------------------------------------------------------------
// transpose_x: x [C=64][L] fp32 -> xt [L][64] f16 (linear, packed dwords)
// ---------------------------------------------------------------------------
__global__ void transpose_x(const float* __restrict__ x, unsigned* __restrict__ xt2)
{
    __shared__ float tile[64][65];
    const int tid = threadIdx.x;
    const int lb  = blockIdx.x * 64;
    const int ln  = tid & 63;
    const int q   = tid >> 6;    // 0..3
#pragma unroll
    for (int i = 0; i < 16; ++i) {
        int c = q + 4 * i;
        tile[ln][c] = x[(size_t)c * L_DIM + lb + ln];
    }
    __syncthreads();
    const int ln2 = tid & 31, q2 = tid >> 5;   // 0..7
#pragma unroll
    for (int i = 0; i < 8; ++i) {
        int ll = q2 + 8 * i;
        __half2 h2 = __float22half2_rn(make_float2(tile[ll][2*ln2], tile[ll][2*ln2+1]));
        xt2[(size_t)(lb + ll) * 32 + ln2] = *reinterpret_cast<unsigned*>(&h2);
    }
}

// ---- per-tap helpers (depth-1 pipeline, R7-proven) -------------------------
#define PARAMS_ISSUE(K, O2) { \
    int kt_ = (K) / 9; int r9_ = (K) - kt_ * 9; \
    int kh_ = r9_ / 3; int kw_ = r9_ - kh_ * 3; \
    int tp_ = t + kt_ - 1; \
    bool tv_ = (tp_ >= 0) && (tp_ < T_DIM); \
    int tb_ = (tv_ ? tp_ : 0) * HW; \
    if (DEFORM) { \
        float ph_ = (float)(h + kh_ - 1) + (O2).x; \
        float pw_ = (float)(w + kw_ - 1) + (O2).y; \
        float h0f_ = floorf(ph_), w0f_ = floorf(pw_); \
        float lh_ = ph_ - h0f_, lw_ = pw_ - w0f_; \
        int h0_ = (int)h0f_, w0_ = (int)w0f_; \
        _Pragma("unroll") \
        for (int j = 0; j < 4; ++j) { \
            int hj_ = h0_ + (j >> 1), wj_ = w0_ + (j & 1); \
            bool v_ = tv_ && (hj_ >= 0) && (hj_ < H_DIM) && (wj_ >= 0) && (wj_ < W_DIM); \
            float wh_  = (j >> 1) ? lh_ : 1.f - lh_; \
            float wwt_ = (j & 1)  ? lw_ : 1.f - lw_; \
            int hc_ = min(max(hj_, 0), H_DIM - 1); \
            int wc_ = min(max(wj_, 0), W_DIM - 1); \
            cwh[j] = __float2half2_rn(v_ ? wh_ * wwt_ : 0.f); \
            int cb_ = (tb_ + hc_ * W_DIM + wc_) * 128 + lk * 16; \
            g[2*j]   = *(const int4*)(xb + cb_); \
            g[2*j+1] = *(const int4*)(xb + cb_ + 64); \
        } \
    } else { \
        int hj_ = h + kh_ - 1, wj_ = w + kw_ - 1; \
        bool v_ = tv_ && (hj_ >= 0) && (hj_ < H_DIM) && (wj_ >= 0) && (wj_ < W_DIM); \
        int hc_ = min(max(hj_, 0), H_DIM - 1); \
        int wc_ = min(max(wj_, 0), W_DIM - 1); \
        cw0 = v_ ? 1.f : 0.f; \
        int cb_ = (tb_ + hc_ * W_DIM + wc_) * 128 + lk * 16; \
        g[0] = *(const int4*)(xb + cb_); \
        g[1] = *(const int4*)(xb + cb_ + 64); \
    } }

#define CONSUME(A0, A1) { \
    if (DEFORM) { \
        __half2 va_[8]; \
        const __half2 z2_ = __float2half2_rn(0.f); \
        _Pragma("unroll") \
        for (int p = 0; p < 8; ++p) va_[p] = z2_; \
        _Pragma("unroll") \
        for (int j = 0; j < 4; ++j) { \
            const __half2* g0_ = (const __half2*)&g[2*j]; \
            const __half2* g1_ = (const __half2*)&g[2*j+1]; \
            _Pragma("unroll") \
            for (int d = 0; d < 4; ++d) { \
                va_[d]     = __hfma2(g0_[d], cwh[j], va_[d]); \
                va_[4 + d] = __hfma2(g1_[d], cwh[j], va_[4 + d]); \
            } \
        } \
        A0 = *reinterpret_cast<f16x8*>(&va_[0]); \
        A1 = *reinterpret_cast<f16x8*>(&va_[4]); \
    } else { \
        int4 z0_ = g[0], z1_ = g[1]; \
        if (cw0 == 0.f) { z0_ = make_int4(0,0,0,0); z1_ = make_int4(0,0,0,0); } \
        A0 = *reinterpret_cast<f16x8*>(&z0_); \
        A1 = *reinterpret_cast<f16x8*>(&z1_); \
    } }

// ---------------------------------------------------------------------------
// dcn_fused: ONE kernel per layer. 512 threads, 128 locs/block, grid 504.
//   Phase A: offset conv (27 taps, integer shift) -> offsets (f16) into LDS.
//   __syncthreads (block-local: offsets are pointwise-consumed).
//   Phase B: deformable conv (27 taps, bilinear) reading offsets from LDS.
// Weights: per-tap 2x8KB LDS dbuf via global_load_lds, counted-vmcnt schedule.
//   EPI 1: +bias+leaky -> f16 [loc][64] (y).  EPI 2: +bias+residual -> f32 NCDHW.
// ---------------------------------------------------------------------------
template<int EPI>
__global__ __launch_bounds__(512, 4)
void dcn_fused(const unsigned short* __restrict__ xin,   // f16 [L][64]
               const unsigned short* __restrict__ Wtoff, // f16 [27][64][64] swz
               const unsigned short* __restrict__ Wtm,   // f16 [27][64][64] swz
               const float* __restrict__ boff,           // [54]
               const float* __restrict__ bmain,          // [64]
               const float* __restrict__ resid,          // f32 NCDHW (EPI==2)
               float* __restrict__ outf,
               unsigned short* __restrict__ outh)
{
    __shared__ __align__(16) unsigned char smem[33792];
    unsigned char* wbuf = smem;            // 2 x 8KB weight double-buffer
    unsigned char* soff = smem + 16384;    // offsets: 128 rows x 132B (33-dword stride)

    const int tid  = threadIdx.x;
    const int wv   = tid >> 6, lane = tid & 63;
    const int lr   = lane & 15, lk = lane >> 4;

    // XCD-contiguous swizzle: 504 = 8 x 63 (bijective)
    const int bid = blockIdx.x;
    const int wg  = (bid & 7) * 63 + (bid >> 3);
    const int t    = wg / 72;
    const int tile = wg - t * 72;
    const int lbase = t * HW + tile * 128 + wv * 16;

    const int mypos = tile * 128 + wv * 16 + lr;
    const int h = mypos / W_DIM;
    const int w = mypos - h * W_DIM;

    const unsigned char* xb = (const unsigned char*)xin;

    // weight B-read slot offsets (2-way, free)
    const int s0 = ((lk + lr) & 7) << 4;
    const int s1 = ((lk + 4 + lr) & 7) << 4;

    int4    g[8];
    __half2 cwh[4];
    float   cw0 = 0.f;

    // ===================== PHASE A: offset conv =====================
    {
        constexpr bool DEFORM = false;
        const unsigned char* wgbl = (const unsigned char*)Wtoff;
        f32x4 acc[4];
#pragma unroll
        for (int n = 0; n < 4; ++n) acc[n] = (f32x4){0.f, 0.f, 0.f, 0.f};

        GLOAD16(wgbl + tid * 16, wbuf + wv * 1024);
        float2 o2z = make_float2(0.f, 0.f);
        PARAMS_ISSUE(0, o2z);

#pragma unroll 1
        for (int k = 0; k < NTAPS; ++k) {
            asm volatile("s_waitcnt vmcnt(2)" ::: "memory");   // drain W(k), keep gathers(k)
            lds_barrier();
            if (k + 1 < NTAPS)
                GLOAD16(wgbl + (size_t)(k + 1) * 8192 + tid * 16,
                        wbuf + (((k + 1) & 1) << 13) + wv * 1024);
            f16x8 a0, a1;
            CONSUME(a0, a1);
            if (k + 1 < NTAPS) { PARAMS_ISSUE(k + 1, o2z); }
            const unsigned char* br = wbuf + ((k & 1) << 13) + lr * 128;
#pragma unroll
            for (int n = 0; n < 4; ++n) {
                f16x8 b0 = *(const f16x8*)(br + n * 2048 + s0);
                f16x8 b1 = *(const f16x8*)(br + n * 2048 + s1);
                acc[n] = __builtin_amdgcn_mfma_f32_16x16x32_f16(a0, b0, acc[n], 0, 0, 0);
                acc[n] = __builtin_amdgcn_mfma_f32_16x16x32_f16(a1, b1, acc[n], 0, 0, 0);
            }
        }

        // epilogue A: +bias, pack to f16, write offsets to LDS [loc][o]
#pragma unroll
        for (int n = 0; n < 4; ++n) {
            int o = n * 16 + lr;
            float bvA = (o < 54) ? boff[o] : 0.f;
#pragma unroll
            for (int i = 0; i < 4; ++i) {
                int bl = wv * 16 + lk * 4 + i;     // block-local loc 0..127
                float vv = acc[n][i] + bvA;
                *(unsigned short*)(soff + bl * 132 + o * 2) =
                    __half_as_ushort(__float2half(vv));
            }
        }
    }
    __syncthreads();   // offsets complete; weight buffers free for phase B

    // ===================== PHASE B: deformable conv =====================
    {
        constexpr bool DEFORM = true;
        const unsigned char* wgbl = (const unsigned char*)Wtm;
        const unsigned char* myoff = soff + (wv * 16 + lr) * 132;
        f32x4 acc[4];
#pragma unroll
        for (int n = 0; n < 4; ++n) acc[n] = (f32x4){0.f, 0.f, 0.f, 0.f};

        GLOAD16(wgbl + tid * 16, wbuf + wv * 1024);
        unsigned u0 = *(const unsigned*)(myoff);
        float2 o2a = __half22float2(*reinterpret_cast<__half2*>(&u0));
        unsigned u1 = *(const unsigned*)(myoff + 4);
        float2 o2n = __half22float2(*reinterpret_cast<__half2*>(&u1));
        PARAMS_ISSUE(0, o2a);

#pragma unroll 1
        for (int k = 0; k < NTAPS; ++k) {
            asm volatile("s_waitcnt vmcnt(8)" ::: "memory");   // drain W(k), keep gathers(k)
            lds_barrier();
            if (k + 1 < NTAPS)
                GLOAD16(wgbl + (size_t)(k + 1) * 8192 + tid * 16,
                        wbuf + (((k + 1) & 1) << 13) + wv * 1024);
            float2 onext = make_float2(0.f, 0.f);
            if (k + 2 < NTAPS) {
                unsigned un = *(const unsigned*)(myoff + 4 * (k + 2));
                onext = __half22float2(*reinterpret_cast<__half2*>(&un));
            }
            f16x8 a0, a1;
            CONSUME(a0, a1);
            if (k + 1 < NTAPS) { PARAMS_ISSUE(k + 1, o2n); }
            o2n = onext;
            const unsigned char* br = wbuf + ((k & 1) << 13) + lr * 128;
#pragma unroll
            for (int n = 0; n < 4; ++n) {
                f16x8 b0 = *(const f16x8*)(br + n * 2048 + s0);
                f16x8 b1 = *(const f16x8*)(br + n * 2048 + s1);
                acc[n] = __builtin_amdgcn_mfma_f32_16x16x32_f16(a0, b0, acc[n], 0, 0, 0);
                acc[n] = __builtin_amdgcn_mfma_f32_16x16x32_f16(a1, b1, acc[n], 0, 0, 0);
            }
        }

        // ---- epilogue. C/D: col = lr (out ch within n*16), row = lk*4+i (loc)
        float bv[4];
#pragma unroll
        for (int n = 0; n < 4; ++n) bv[n] = bmain[n * 16 + lr];

        if (EPI == 1) {
#pragma unroll
            for (int n = 0; n < 4; ++n)
#pragma unroll
                for (int i = 0; i < 4; ++i) {
                    int row = lk * 4 + i;
                    float vv = acc[n][i] + bv[n];
                    vv = (vv > 0.f) ? vv : 0.1f * vv;
                    outh[(size_t)(lbase + row) * 64 + n * 16 + lr] =
                        __half_as_ushort(__float2half(vv));
                }
        } else {
            __syncthreads();   // wbuf+soff dead; per-wave 4KB transpose regions
            float* tf = (float*)(smem + (wv << 12));
#pragma unroll
            for (int n = 0; n < 4; ++n)
#pragma unroll
                for (int i = 0; i < 4; ++i) {
                    int row = lk * 4 + i;
                    int och = n * 16 + lr;
                    tf[row * 64 + ((och + 2 * row) & 63)] = acc[n][i] + bv[n];
                }
            asm volatile("s_waitcnt lgkmcnt(0)" ::: "memory");
            __builtin_amdgcn_sched_barrier(0);
            int j = lane & 15, gq = lane >> 4;
#pragma unroll
            for (int it = 0; it < 16; ++it) {
                int och = gq * 16 + it;
                float val = tf[j * 64 + ((och + 2 * j) & 63)];
                size_t gi = (size_t)och * L_DIM + lbase + j;
                outf[gi] = val + resid[gi];
            }
        }
    }
}

// ---------------------------------------------------------------------------
extern "C" void kernel_launch(void* const* d_in, const int* in_sizes, int n_in,
                              void* d_out, int out_size, void* d_ws, size_t ws_size,
                              hipStream_t stream)
{
    const float* x     = (const float*)d_in[0];
    const float* woff0 = (const float*)d_in[1];
    const float* boff0 = (const float*)d_in[2];
    const float* w0    = (const float*)d_in[3];
    const float* b0    = (const float*)d_in[4];
    const float* woff1 = (const float*)d_in[5];
    const float* boff1 = (const float*)d_in[6];
    const float* w1    = (const float*)d_in[7];
    const float* b1    = (const float*)d_in[8];
    float* out = (float*)d_out;

    unsigned char* ws = (unsigned char*)d_ws;
    unsigned short* Wt  = (unsigned short*)ws;                  // 884736 B (4x f16 [27][64][64] swz)
    unsigned short* xt  = (unsigned short*)(ws + 884736);       // 8257536 B f16 [L][64]
    unsigned short* y   = (unsigned short*)(ws + 9142272);      // 8257536 B f16 [L][64]

    prep_weights<<<1728, 256, 0, stream>>>(woff0, w0, woff1, w1, Wt);
    transpose_x<<<1008, 256, 0, stream>>>(x, (unsigned*)xt);

    const int grid = T_DIM * (HW / 128);  // 504 blocks x 512 threads
    const int WSZ  = NTAPS * 64 * 64;     // 110592

    // layer 0 (fused offset-conv + deform + leaky) : xt -> y
    dcn_fused<1><<<grid, 512, 0, stream>>>(xt, Wt,           Wt + WSZ,     boff0, b0, nullptr, nullptr, y);
    // layer 1 (fused offset-conv + deform + residual) : y -> out
    dcn_fused<2><<<grid, 512, 0, stream>>>(y,  Wt + 2 * WSZ, Wt + 3 * WSZ, boff1, b1, x, out, nullptr);
}